// Round 6
// baseline (162.614 us; speedup 1.0000x reference)
//
#include <hip/hip_runtime.h>
#include <hip/hip_bf16.h>

// Shapes (fixed by the problem)
#define NB   16    // batch
#define NC   512   // channels
#define NSPA 1024  // h*w
#define NO3  1536  // 3*C
#define GN_EPS 1e-5f
#define SCL 0.044194173824159216f  // 512^-0.5

typedef __bf16 bf16x8 __attribute__((ext_vector_type(8)));
typedef __bf16 bf16x4 __attribute__((ext_vector_type(4)));
typedef float  f32x4  __attribute__((ext_vector_type(4)));

typedef __attribute__((address_space(3))) void lds_t;
typedef const __attribute__((address_space(1))) void gl_t;
#define GLDS16(g, l) __builtin_amdgcn_global_load_lds((gl_t*)(g), (lds_t*)(l), 16, 0, 0)

__device__ __forceinline__ __bf16 tob(float f) { return (__bf16)f; }

// barrier + compiler fence (stops IR-level hoisting of LDS reads above it;
// per-wave vmcnt only certifies own loads — cross-wave visibility = barrier)
#define SBAR do { __builtin_amdgcn_s_barrier(); asm volatile("" ::: "memory"); } while (0)

// ---------------------------------------------------------------------------
// K1: GroupNorm stats -> per (b,c) affine coefs: xn = x*coefA + coefB
// ---------------------------------------------------------------------------
__global__ void gn_stats_kernel(const float* __restrict__ x,
                                const float* __restrict__ gn_scale,
                                const float* __restrict__ gn_bias,
                                float* __restrict__ coefA,
                                float* __restrict__ coefB) {
  const int bg = blockIdx.x;
  const int b = bg >> 5, g = bg & 31;
  const float4* base = (const float4*)(x + (size_t)(b * NC + g * 16) * NSPA);
  const int tid = threadIdx.x;
  float s = 0.f, ss = 0.f;
#pragma unroll
  for (int i = 0; i < 16; ++i) {
    float4 v = base[i * 256 + tid];
    s  += (v.x + v.y) + (v.z + v.w);
    ss += (v.x * v.x + v.y * v.y) + (v.z * v.z + v.w * v.w);
  }
#pragma unroll
  for (int off = 32; off; off >>= 1) {
    s  += __shfl_xor(s, off);
    ss += __shfl_xor(ss, off);
  }
  __shared__ float rs[4], rss[4];
  const int wave = tid >> 6, lane = tid & 63;
  if (lane == 0) { rs[wave] = s; rss[wave] = ss; }
  __syncthreads();
  if (tid < 16) {
    float S  = rs[0] + rs[1] + rs[2] + rs[3];
    float SS = rss[0] + rss[1] + rss[2] + rss[3];
    float mean = S * (1.f / 16384.f);
    float var  = SS * (1.f / 16384.f) - mean * mean;
    float rstd = rsqrtf(var + GN_EPS);
    int c = g * 16 + tid;
    float a = gn_scale[c] * rstd;
    coefA[b * NC + c] = a;
    coefB[b * NC + c] = gn_bias[c] - mean * a;
  }
}

// ---------------------------------------------------------------------------
// K2a: pack weights fp32 -> bf16, natural [o][c]
// ---------------------------------------------------------------------------
__global__ void pack_w_kernel(const float* __restrict__ wq, const float* __restrict__ wo,
                              __bf16* __restrict__ wqb, __bf16* __restrict__ wob) {
  const int t = blockIdx.x * 256 + threadIdx.x;
  const int NQ = NO3 * NC / 4;
  float4 v;
  __bf16* dst;
  if (t < NQ) { v = ((const float4*)wq)[t]; dst = wqb + (size_t)t * 4; }
  else        { v = ((const float4*)wo)[t - NQ]; dst = wob + (size_t)(t - NQ) * 4; }
  bf16x4 w;
  w[0] = tob(v.x); w[1] = tob(v.y); w[2] = tob(v.z); w[3] = tob(v.w);
  *(bf16x4*)dst = w;
}

// ---------------------------------------------------------------------------
// K2b: xnT[b][n][c] = bf16(GN(x))  (64c x 64n LDS transpose tiles)
// ---------------------------------------------------------------------------
__global__ void pack_x_kernel(const float* __restrict__ x,
                              const float* __restrict__ coefA,
                              const float* __restrict__ coefB,
                              __bf16* __restrict__ xnT) {
  const int n0 = blockIdx.x * 64, c0 = blockIdx.y * 64, b = blockIdx.z;
  __shared__ __bf16 l[64][72];  // [n][c]
  const int tid = threadIdx.x;
  const int cl = tid >> 2, seg = (tid & 3) * 16;
  const float ca = coefA[b * NC + c0 + cl], cb = coefB[b * NC + c0 + cl];
  const float4* src = (const float4*)(x + (size_t)(b * NC + c0 + cl) * NSPA + n0 + seg);
#pragma unroll
  for (int i = 0; i < 4; ++i) {
    float4 v = src[i];
    l[seg + i * 4 + 0][cl] = tob(v.x * ca + cb);
    l[seg + i * 4 + 1][cl] = tob(v.y * ca + cb);
    l[seg + i * 4 + 2][cl] = tob(v.z * ca + cb);
    l[seg + i * 4 + 3][cl] = tob(v.w * ca + cb);
  }
  __syncthreads();
#pragma unroll
  for (int i = 0; i < 2; ++i) {
    const int chunk = tid + i * 256;
    const int row = chunk >> 3, s = chunk & 7;
    *(bf16x8*)(xnT + (size_t)(b * NSPA + n0 + row) * NC + c0 + s * 8) =
        *(const bf16x8*)&l[row][s * 8];
  }
}

// ===========================================================================
// 8-phase GEMM core v2 (m201-faithful stagger). BK=64, 512 thr = 8 waves.
// MREP=8: block 256x256; MREP=4: block 128x256. Per phase: {ds_read one
// m/n-half's frags | stage ONE half of tile T+1 | counted vmcnt | barrier |
// 16 (or 8) MFMA | barrier}.  Each staged half gets ~3 phases before its
// certify-wait, and is certified one phase before its ds_read.
//
// Halves are CONTIGUOUS 128-row (A: MREP*16) regions; wave ownership is
// interleaved INSIDE a half so phase-p reads touch exactly that half:
//   A rows:  m(mi) = (mi>=MH)*AH + wrow*AH/2 + (mi%MH)*16 + r
//   B rows:  n(ni) = (ni>=2)*128 + wcol*32 + (ni%2)*16 + c
// Stage stream per tile T (into buf^1): P1:A0' P2:B0' P3:B1' P4:A1'.
// Certify ledger (allow = last two stages outstanding):
//   end-P1 {A1',A0''}  end-P2 {A0'',B0''}? -> constants per MREP below.
//   A0' cert end-P3(T-1)->read P1(T); B0' end-P4(T-1)->P1(T);
//   B1' end-P1(T)->P2(T); A1' end-P2(T)->P3(T).   WAR gaps >= 4 phases.
// XOR swizzle (r3-proven 0-conflict): phys chunk pc of row r holds global
// chunk pc^(r&7); reads XOR the same. Half offsets are multiples of 8 rows
// so relative==absolute (row&7).
// ===========================================================================
template <int ROWS>
__device__ __forceinline__ void stage_half(const __bf16* __restrict__ src, int ld,
                                           int k0, __bf16* dst) {
  const int tid = threadIdx.x;
#pragma unroll
  for (int l = 0; l < ROWS / 64; ++l) {
    const int idx = tid + l * 512;
    const int prow = idx >> 3;
    const int pcs = (idx & 7) ^ (prow & 7);
    GLDS16(src + (size_t)prow * ld + k0 + pcs * 8, dst + idx * 8);
  }
}

template <int MH>
__device__ __forceinline__ void read_af(const __bf16* tile, int mh, int wrow,
                                        int fr, int fgh, bf16x8 af[][2]) {
#pragma unroll
  for (int mi = 0; mi < MH; ++mi)
#pragma unroll
    for (int ks = 0; ks < 2; ++ks) {
      const int row = mh * (MH * 32) + wrow * (MH * 16) + mi * 16 + fr;
      const int c = ks * 4 + fgh;
      af[mi][ks] = *(const bf16x8*)&tile[row * 64 + ((c ^ (row & 7)) * 8)];
    }
}

__device__ __forceinline__ void read_bf(const __bf16* tile, int nh, int wcol,
                                        int fr, int fgh, bf16x8 bb[2][2]) {
#pragma unroll
  for (int ni = 0; ni < 2; ++ni)
#pragma unroll
    for (int ks = 0; ks < 2; ++ks) {
      const int row = nh * 128 + wcol * 32 + ni * 16 + fr;
      const int c = ks * 4 + fgh;
      bb[ni][ks] = *(const bf16x8*)&tile[row * 64 + ((c ^ (row & 7)) * 8)];
    }
}

template <int MH>
__device__ __forceinline__ void mfma_q(bf16x8 af[][2], bf16x8 bb[2][2],
                                       int mh, int nh, f32x4 (*acc)[4]) {
  __builtin_amdgcn_s_setprio(1);
#pragma unroll
  for (int mi = 0; mi < MH; ++mi)
#pragma unroll
    for (int ni = 0; ni < 2; ++ni)
#pragma unroll
      for (int ks = 0; ks < 2; ++ks)
        acc[mh * MH + mi][nh * 2 + ni] = __builtin_amdgcn_mfma_f32_16x16x32_bf16(
            af[mi][ks], bb[ni][ks], acc[mh * MH + mi][nh * 2 + ni], 0, 0, 0);
  __builtin_amdgcn_s_setprio(0);
}

template <int MREP>
__device__ __forceinline__ void gemm8p(const __bf16* __restrict__ Ag, int lda,
                                       const __bf16* __restrict__ Bg, int ldb,
                                       int NT, __bf16* sA, __bf16* sB,
                                       f32x4 (*acc)[4]) {
  constexpr int MH = MREP / 2;
  constexpr int AH = MREP * 16;        // A-half rows (128 or 64)
  constexpr int ATILE = AH * 2 * 64;   // elems per A buffer
  constexpr int BTILE = 256 * 64;
  const int tid = threadIdx.x;
  const int lane = tid & 63, wave = tid >> 6;
  const int wrow = wave >> 2, wcol = wave & 3;
  const int fr = lane & 15, fgh = lane >> 4;

  // prologue: tile 0 halves in stream order A0,B0,B1,A1; certify A0,B0.
  stage_half<AH>(Ag, lda, 0, sA);
  stage_half<128>(Bg, ldb, 0, sB);
  stage_half<128>(Bg + (size_t)128 * ldb, ldb, 0, sB + 128 * 64);
  stage_half<AH>(Ag + (size_t)AH * lda, lda, 0, sA + AH * 64);
  if constexpr (MREP == 8) asm volatile("s_waitcnt vmcnt(4)" ::: "memory");
  else                     asm volatile("s_waitcnt vmcnt(3)" ::: "memory");
  SBAR;

  bf16x8 af[MH][2], b0[2][2], b1[2][2];

  for (int T = 0; T < NT; ++T) {
    const int buf = T & 1;
    const __bf16* cA = sA + buf * ATILE;
    const __bf16* cB = sB + buf * BTILE;
    __bf16* nA = sA + (buf ^ 1) * ATILE;
    __bf16* nB = sB + (buf ^ 1) * BTILE;
    const int kn = (T + 1) * 64;
    const bool pf = (T + 1 < NT);
    // ---- P1: read A0,B0 of T; stage A0(T+1); certify B1(T)
    read_af<MH>(cA, 0, wrow, fr, fgh, af);
    read_bf(cB, 0, wcol, fr, fgh, b0);
    if (pf) stage_half<AH>(Ag, lda, kn, nA);
    if constexpr (MREP == 8) asm volatile("s_waitcnt vmcnt(4)" ::: "memory");
    else                     asm volatile("s_waitcnt vmcnt(2)" ::: "memory");
    SBAR;
    mfma_q<MH>(af, b0, 0, 0, acc);
    SBAR;
    // ---- P2: read B1(T); stage B0(T+1); certify A1(T)
    read_bf(cB, 1, wcol, fr, fgh, b1);
    if (pf) stage_half<128>(Bg, ldb, kn, nB);
    if constexpr (MREP == 8) asm volatile("s_waitcnt vmcnt(4)" ::: "memory");
    else                     asm volatile("s_waitcnt vmcnt(3)" ::: "memory");
    SBAR;
    mfma_q<MH>(af, b1, 0, 1, acc);
    SBAR;
    // ---- P3: read A1(T); stage B1(T+1); certify A0(T+1)
    read_af<MH>(cA, 1, wrow, fr, fgh, af);
    if (pf) stage_half<128>(Bg + (size_t)128 * ldb, ldb, kn, nB + 128 * 64);
    asm volatile("s_waitcnt vmcnt(4)" ::: "memory");
    SBAR;
    mfma_q<MH>(af, b1, 1, 1, acc);
    SBAR;
    // ---- P4: no reads (af=A1, b0 resident); stage A1(T+1); certify B0(T+1)
    if (pf) stage_half<AH>(Ag + (size_t)AH * lda, lda, kn, nA + AH * 64);
    if constexpr (MREP == 8) asm volatile("s_waitcnt vmcnt(4)" ::: "memory");
    else                     asm volatile("s_waitcnt vmcnt(3)" ::: "memory");
    SBAR;
    mfma_q<MH>(af, b0, 1, 0, acc);
    SBAR;
  }
}

// C-index helpers for the interleaved half layout
#define MROW8(mi) (((mi) >> 2) * 128 + wrow * 64 + ((mi) & 3) * 16)
#define MROW4(mi) (((mi) >> 1) * 64 + wrow * 32 + ((mi) & 1) * 16)
#define NCOL(ni)  ((((ni) >> 1) * 128) + wcol * 32 + (((ni) & 1) * 16))

// ---------------------------------------------------------------------------
// K3: QKV GEMM (8-phase 256^2). C[o][n] = Wqkv[o][c] x xnT[n][c]^T (+bias).
//   o <  1024 (q,k): transposed store -> qk[b][n][o]
//   o >= 1024 (v)  : natural store    -> v[b][o-1024][n]
// grid (4, 6, NB) x 512 thr
// ---------------------------------------------------------------------------
__global__ __launch_bounds__(512, 2) void qkv_gemm_kernel(
    const __bf16* __restrict__ wqb, const __bf16* __restrict__ xnT,
    const float* __restrict__ bqkv, __bf16* __restrict__ qk, __bf16* __restrict__ v) {
  const int n0 = blockIdx.x * 256, m0 = blockIdx.y * 256, b = blockIdx.z;
  __shared__ __align__(16) __bf16 sA[2 * 256 * 64];  // 64 KB
  __shared__ __align__(16) __bf16 sB[2 * 256 * 64];  // 64 KB
  f32x4 acc[8][4] = {};
  gemm8p<8>(wqb + (size_t)m0 * NC, NC, xnT + ((size_t)b * NSPA + n0) * NC, NC,
            NC / 64, sA, sB, acc);

  const int lane = threadIdx.x & 63, wave = threadIdx.x >> 6;
  const int wrow = wave >> 2, wcol = wave & 3;
  const int fr = lane & 15, fq4 = (lane >> 4) * 4;
  if (m0 < NSPA) {
#pragma unroll
    for (int mi = 0; mi < 8; ++mi) {
      const int m = m0 + MROW8(mi) + fq4;
      const float4 bias = *(const float4*)(bqkv + m);
#pragma unroll
      for (int ni = 0; ni < 4; ++ni) {
        const int n = n0 + NCOL(ni) + fr;
        bf16x4 w;
        w[0] = tob(acc[mi][ni][0] + bias.x);
        w[1] = tob(acc[mi][ni][1] + bias.y);
        w[2] = tob(acc[mi][ni][2] + bias.z);
        w[3] = tob(acc[mi][ni][3] + bias.w);
        *(bf16x4*)(qk + ((size_t)b * NSPA + n) * NSPA + m) = w;
      }
    }
  } else {
#pragma unroll
    for (int mi = 0; mi < 8; ++mi) {
      const int m = m0 + MROW8(mi) + fq4;
      const float4 bias = *(const float4*)(bqkv + m);
      const int vr = m - NSPA;
#pragma unroll
      for (int ni = 0; ni < 4; ++ni) {
        const int n = n0 + NCOL(ni) + fr;
        v[((size_t)b * NC + vr + 0) * NSPA + n] = tob(acc[mi][ni][0] + bias.x);
        v[((size_t)b * NC + vr + 1) * NSPA + n] = tob(acc[mi][ni][1] + bias.y);
        v[((size_t)b * NC + vr + 2) * NSPA + n] = tob(acc[mi][ni][2] + bias.z);
        v[((size_t)b * NC + vr + 3) * NSPA + n] = tob(acc[mi][ni][3] + bias.w);
      }
    }
  }
}

// ---------------------------------------------------------------------------
// K4: scores (swapped, 8-phase 256^2). C[j][i] = k[j][d].q[i][d];
// store P[b][i][j]*SCL.  grid (4, 4, NB) x 512 thr
// ---------------------------------------------------------------------------
__global__ __launch_bounds__(512, 2) void scores_kernel(const __bf16* __restrict__ qk,
                                                        __bf16* __restrict__ P) {
  const int i0 = blockIdx.x * 256, j0 = blockIdx.y * 256, b = blockIdx.z;
  const __bf16* base = qk + (size_t)b * NSPA * NSPA;
  __shared__ __align__(16) __bf16 sA[2 * 256 * 64];
  __shared__ __align__(16) __bf16 sB[2 * 256 * 64];
  f32x4 acc[8][4] = {};
  gemm8p<8>(base + (size_t)j0 * NSPA + NC, NSPA, base + (size_t)i0 * NSPA, NSPA,
            NC / 64, sA, sB, acc);

  const int lane = threadIdx.x & 63, wave = threadIdx.x >> 6;
  const int wrow = wave >> 2, wcol = wave & 3;
  const int fr = lane & 15, fq4 = (lane >> 4) * 4;
#pragma unroll
  for (int mi = 0; mi < 8; ++mi) {
    const int j = j0 + MROW8(mi) + fq4;
#pragma unroll
    for (int ni = 0; ni < 4; ++ni) {
      const int i = i0 + NCOL(ni) + fr;
      bf16x4 w;
      w[0] = tob(acc[mi][ni][0] * SCL);
      w[1] = tob(acc[mi][ni][1] * SCL);
      w[2] = tob(acc[mi][ni][2] * SCL);
      w[3] = tob(acc[mi][ni][3] * SCL);
      *(bf16x4*)(P + ((size_t)b * NSPA + i) * NSPA + j) = w;
    }
  }
}

// ---------------------------------------------------------------------------
// K5: in-place row softmax, one WAVE per row (4 rows/block, shuffle-only).
// ---------------------------------------------------------------------------
__global__ void softmax_kernel(__bf16* __restrict__ P) {
  const int row = blockIdx.x * 4 + (threadIdx.x >> 6);
  const int lane = threadIdx.x & 63;
  __bf16* p = P + (size_t)row * NSPA + lane * 16;
  bf16x8 v0 = *(const bf16x8*)p;
  bf16x8 v1 = *(const bf16x8*)(p + 8);
  float f[16];
#pragma unroll
  for (int i = 0; i < 8; ++i) { f[i] = (float)v0[i]; f[8 + i] = (float)v1[i]; }
  float m = f[0];
#pragma unroll
  for (int i = 1; i < 16; ++i) m = fmaxf(m, f[i]);
#pragma unroll
  for (int off = 32; off; off >>= 1) m = fmaxf(m, __shfl_xor(m, off));
  float s = 0.f;
#pragma unroll
  for (int i = 0; i < 16; ++i) { f[i] = __expf(f[i] - m); s += f[i]; }
#pragma unroll
  for (int off = 32; off; off >>= 1) s += __shfl_xor(s, off);
  const float inv = 1.f / s;
#pragma unroll
  for (int i = 0; i < 8; ++i) { v0[i] = tob(f[i] * inv); v1[i] = tob(f[8 + i] * inv); }
  *(bf16x8*)p = v0;
  *(bf16x8*)(p + 8) = v1;
}

// ---------------------------------------------------------------------------
// K6: PV (8-phase 128x256, MREP=4). C[d][i] = v[d][j].P[i][j];
// transposed store -> attn[b][i][d].  grid (4 i, 4 d, NB) x 512 thr, NT=16
// ---------------------------------------------------------------------------
__global__ __launch_bounds__(512, 2) void pv_kernel(const __bf16* __restrict__ v,
                                                    const __bf16* __restrict__ P,
                                                    __bf16* __restrict__ attn) {
  const int i0 = blockIdx.x * 256, d0 = blockIdx.y * 128, b = blockIdx.z;
  __shared__ __align__(16) __bf16 sA[2 * 128 * 64];  // 32 KB
  __shared__ __align__(16) __bf16 sB[2 * 256 * 64];  // 64 KB
  f32x4 acc[4][4] = {};
  gemm8p<4>(v + ((size_t)b * NC + d0) * NSPA, NSPA,
            P + ((size_t)b * NSPA + i0) * NSPA, NSPA, NSPA / 64, sA, sB, acc);

  const int lane = threadIdx.x & 63, wave = threadIdx.x >> 6;
  const int wrow = wave >> 2, wcol = wave & 3;
  const int fr = lane & 15, fq4 = (lane >> 4) * 4;
#pragma unroll
  for (int mi = 0; mi < 4; ++mi) {
    const int d = d0 + MROW4(mi) + fq4;
#pragma unroll
    for (int ni = 0; ni < 4; ++ni) {
      const int i = i0 + NCOL(ni) + fr;
      bf16x4 w;
      w[0] = tob(acc[mi][ni][0]);
      w[1] = tob(acc[mi][ni][1]);
      w[2] = tob(acc[mi][ni][2]);
      w[3] = tob(acc[mi][ni][3]);
      *(bf16x4*)(attn + ((size_t)b * NSPA + i) * NC + d) = w;
    }
  }
}

// ---------------------------------------------------------------------------
// K7: out-proj (8-phase 128x256, MREP=4). C[o][n] = Wout[o][c].attn[n][c]
// + bias + x, fp32 natural.  grid (4 n, 4 m, NB) x 512 thr, NT=8
// ---------------------------------------------------------------------------
__global__ __launch_bounds__(512, 2) void out_gemm_kernel(
    const __bf16* __restrict__ wob, const __bf16* __restrict__ attn,
    const float* __restrict__ bout, const float* __restrict__ x,
    float* __restrict__ out) {
  const int n0 = blockIdx.x * 256, m0 = blockIdx.y * 128, b = blockIdx.z;
  __shared__ __align__(16) __bf16 sA[2 * 128 * 64];
  __shared__ __align__(16) __bf16 sB[2 * 256 * 64];
  f32x4 acc[4][4] = {};
  gemm8p<4>(wob + (size_t)m0 * NC, NC, attn + ((size_t)b * NSPA + n0) * NC, NC,
            NC / 64, sA, sB, acc);

  const int lane = threadIdx.x & 63, wave = threadIdx.x >> 6;
  const int wrow = wave >> 2, wcol = wave & 3;
  const int fr = lane & 15, fq4 = (lane >> 4) * 4;
#pragma unroll
  for (int mi = 0; mi < 4; ++mi) {
    const int m = m0 + MROW4(mi) + fq4;
    const float4 bias = *(const float4*)(bout + m);
#pragma unroll
    for (int ni = 0; ni < 4; ++ni) {
      const int n = n0 + NCOL(ni) + fr;
      const size_t i0x = ((size_t)b * NC + m) * NSPA + n;
      out[i0x + 0 * NSPA] = acc[mi][ni][0] + bias.x + x[i0x + 0 * NSPA];
      out[i0x + 1 * NSPA] = acc[mi][ni][1] + bias.y + x[i0x + 1 * NSPA];
      out[i0x + 2 * NSPA] = acc[mi][ni][2] + bias.z + x[i0x + 2 * NSPA];
      out[i0x + 3 * NSPA] = acc[mi][ni][3] + bias.w + x[i0x + 3 * NSPA];
    }
  }
}

// ---------------------------------------------------------------------------
// Workspace (~66 MB):
//   coefA/coefB: 2x32 KB | xnT/attn: 16 MB | wqb 1.5 MB | wob 0.5 MB
//   v: 16 MB | P: 32 MB.  qk (32 MB) lives in d_out (dead until out_gemm).
// ---------------------------------------------------------------------------
extern "C" void kernel_launch(void* const* d_in, const int* in_sizes, int n_in,
                              void* d_out, int out_size, void* d_ws, size_t ws_size,
                              hipStream_t stream) {
  const float* x        = (const float*)d_in[0];
  const float* gn_scale = (const float*)d_in[3];
  const float* gn_bias  = (const float*)d_in[4];
  const float* w_qkv    = (const float*)d_in[5];
  const float* b_qkv    = (const float*)d_in[6];
  const float* w_out    = (const float*)d_in[7];
  const float* b_out    = (const float*)d_in[8];
  float* out = (float*)d_out;

  char* ws = (char*)d_ws;
  float*  coefA = (float*)ws;                                   // 32 KB
  float*  coefB = coefA + NB * NC;                              // 32 KB
  __bf16* xnT   = (__bf16*)(ws + (64 << 10));                   // 16 MB (also attn)
  __bf16* attn  = xnT;
  __bf16* wqb   = xnT + (size_t)NB * NSPA * NC;                 // 1.5 MB
  __bf16* wob   = wqb + (size_t)NO3 * NC;                       // 0.5 MB
  __bf16* vbuf  = wob + (size_t)NC * NC;                        // 16 MB
  __bf16* P     = vbuf + (size_t)NB * NC * NSPA;                // 32 MB
  __bf16* qk    = (__bf16*)d_out;                               // 32 MB scratch in out

  gn_stats_kernel<<<dim3(NB * 32), 256, 0, stream>>>(x, gn_scale, gn_bias, coefA, coefB);
  pack_w_kernel<<<dim3((NO3 * NC + NC * NC) / 4 / 256), 256, 0, stream>>>(w_qkv, w_out, wqb, wob);
  pack_x_kernel<<<dim3(NSPA / 64, NC / 64, NB), 256, 0, stream>>>(x, coefA, coefB, xnT);
  qkv_gemm_kernel<<<dim3(4, 6, NB), 512, 0, stream>>>(wqb, xnT, b_qkv, qk, vbuf);
  scores_kernel<<<dim3(4, 4, NB), 512, 0, stream>>>(qk, P);
  softmax_kernel<<<dim3(NB * NSPA / 4), 256, 0, stream>>>(P);
  pv_kernel<<<dim3(4, 4, NB), 512, 0, stream>>>(vbuf, P, attn);
  out_gemm_kernel<<<dim3(4, 4, NB), 512, 0, stream>>>(wob, attn, b_out, x, out);
}

// Round 7
// 134.405 us; speedup vs baseline: 1.2099x; 1.2099x over previous
//
#include <hip/hip_runtime.h>
#include <hip/hip_bf16.h>

// Shapes (fixed by the problem)
#define NB   16    // batch
#define NC   512   // channels
#define NSPA 1024  // h*w
#define NO3  1536  // 3*C
#define GN_EPS 1e-5f
#define SCL 0.044194173824159216f  // 512^-0.5

typedef __bf16 bf16x8 __attribute__((ext_vector_type(8)));
typedef __bf16 bf16x4 __attribute__((ext_vector_type(4)));
typedef float  f32x4  __attribute__((ext_vector_type(4)));

typedef __attribute__((address_space(3))) void lds_t;
typedef const __attribute__((address_space(1))) void gl_t;
#define GLDS16(g, l) __builtin_amdgcn_global_load_lds((gl_t*)(g), (lds_t*)(l), 16, 0, 0)

__device__ __forceinline__ __bf16 tob(float f) { return (__bf16)f; }

// Bijective XCD-chunk swizzle (T1, m204 form for nwg%8==0): hardware
// round-robins blockIdx across 8 XCDs; remap so each XCD gets a CONTIGUOUS
// logical chunk. All swizzled grids have nwg % 8 == 0.
__device__ __forceinline__ int xcd_swz(int cpx) {
  return (blockIdx.x & 7) * cpx + (blockIdx.x >> 3);
}

// ---------------------------------------------------------------------------
// K1: GroupNorm stats -> per (b,c) affine coefs: xn = x*coefA + coefB
// 1D grid 512 (CPX=64): XCD = L/64 = b/2  (batch b = L>>5)
// ---------------------------------------------------------------------------
__global__ void gn_stats_kernel(const float* __restrict__ x,
                                const float* __restrict__ gn_scale,
                                const float* __restrict__ gn_bias,
                                float* __restrict__ coefA,
                                float* __restrict__ coefB) {
  const int L = xcd_swz(64);
  const int b = L >> 5, g = L & 31;
  const float4* base = (const float4*)(x + (size_t)(b * NC + g * 16) * NSPA);
  const int tid = threadIdx.x;
  float s = 0.f, ss = 0.f;
#pragma unroll
  for (int i = 0; i < 16; ++i) {
    float4 v = base[i * 256 + tid];
    s  += (v.x + v.y) + (v.z + v.w);
    ss += (v.x * v.x + v.y * v.y) + (v.z * v.z + v.w * v.w);
  }
#pragma unroll
  for (int off = 32; off; off >>= 1) {
    s  += __shfl_xor(s, off);
    ss += __shfl_xor(ss, off);
  }
  __shared__ float rs[4], rss[4];
  const int wave = tid >> 6, lane = tid & 63;
  if (lane == 0) { rs[wave] = s; rss[wave] = ss; }
  __syncthreads();
  if (tid < 16) {
    float S  = rs[0] + rs[1] + rs[2] + rs[3];
    float SS = rss[0] + rss[1] + rss[2] + rss[3];
    float mean = S * (1.f / 16384.f);
    float var  = SS * (1.f / 16384.f) - mean * mean;
    float rstd = rsqrtf(var + GN_EPS);
    int c = g * 16 + tid;
    float a = gn_scale[c] * rstd;
    coefA[b * NC + c] = a;
    coefB[b * NC + c] = gn_bias[c] - mean * a;
  }
}

// ---------------------------------------------------------------------------
// K2a: pack weights fp32 -> bf16, natural [o][c] (small; no swizzle)
// ---------------------------------------------------------------------------
__global__ void pack_w_kernel(const float* __restrict__ wq, const float* __restrict__ wo,
                              __bf16* __restrict__ wqb, __bf16* __restrict__ wob) {
  const int t = blockIdx.x * 256 + threadIdx.x;
  const int NQ = NO3 * NC / 4;
  float4 v;
  __bf16* dst;
  if (t < NQ) { v = ((const float4*)wq)[t]; dst = wqb + (size_t)t * 4; }
  else        { v = ((const float4*)wo)[t - NQ]; dst = wob + (size_t)(t - NQ) * 4; }
  bf16x4 w;
  w[0] = tob(v.x); w[1] = tob(v.y); w[2] = tob(v.z); w[3] = tob(v.w);
  *(bf16x4*)dst = w;
}

// ---------------------------------------------------------------------------
// K2b: xnT[b][n][c] = bf16(GN(x))  (64c x 64n LDS transpose tiles)
// 1D grid 2048 (CPX=256): XCD = L/256 = b/2  (b = L>>7) — produces xnT[b]
// on the SAME XCD that qkv will consume it on.
// ---------------------------------------------------------------------------
__global__ void pack_x_kernel(const float* __restrict__ x,
                              const float* __restrict__ coefA,
                              const float* __restrict__ coefB,
                              __bf16* __restrict__ xnT) {
  const int L = xcd_swz(256);
  const int b = L >> 7, rem = L & 127;
  const int c0 = (rem >> 4) * 64, n0 = (rem & 15) * 64;
  __shared__ __bf16 l[64][72];  // [n][c]
  const int tid = threadIdx.x;
  const int cl = tid >> 2, seg = (tid & 3) * 16;
  const float ca = coefA[b * NC + c0 + cl], cb = coefB[b * NC + c0 + cl];
  const float4* src = (const float4*)(x + (size_t)(b * NC + c0 + cl) * NSPA + n0 + seg);
#pragma unroll
  for (int i = 0; i < 4; ++i) {
    float4 v = src[i];
    l[seg + i * 4 + 0][cl] = tob(v.x * ca + cb);
    l[seg + i * 4 + 1][cl] = tob(v.y * ca + cb);
    l[seg + i * 4 + 2][cl] = tob(v.z * ca + cb);
    l[seg + i * 4 + 3][cl] = tob(v.w * ca + cb);
  }
  __syncthreads();
#pragma unroll
  for (int i = 0; i < 2; ++i) {
    const int chunk = tid + i * 256;
    const int row = chunk >> 3, s = chunk & 7;
    *(bf16x8*)(xnT + (size_t)(b * NSPA + n0 + row) * NC + c0 + s * 8) =
        *(const bf16x8*)&l[row][s * 8];
  }
}

// ---------------------------------------------------------------------------
// r3 2-phase 128^2 core (proven): XOR-swizzled LDS (0 conflicts), dbuf,
// setprio around MFMA cluster.
// ---------------------------------------------------------------------------
__device__ __forceinline__ void stage_pair(const __bf16* __restrict__ A, int lda,
                                           const __bf16* __restrict__ B, int ldb,
                                           int k0, __bf16* lAf, __bf16* lBf) {
  const int tid = threadIdx.x;
#pragma unroll
  for (int i = 0; i < 4; ++i) {
    const int idx = tid + i * 256;
    const int srow = idx >> 3;
    const int ss = ((idx & 7) ^ (srow & 7)) * 8;  // inverse-swizzled source chunk
    GLDS16(A + (size_t)srow * lda + k0 + ss, lAf + idx * 8);
    GLDS16(B + (size_t)srow * ldb + k0 + ss, lBf + idx * 8);
  }
}

__device__ __forceinline__ void gemm_core_db(const __bf16* __restrict__ A, int lda,
                                             const __bf16* __restrict__ B, int ldb,
                                             int K, __bf16 (*lA)[128][64],
                                             __bf16 (*lB)[128][64], f32x4 acc[4][4]) {
  const int tid = threadIdx.x;
  const int lane = tid & 63, wave = tid >> 6;
  const int wm = (wave >> 1) * 64, wn = (wave & 1) * 64;
  const int fr = lane & 15, fg = (lane >> 4) * 8;
  const int nt = K >> 6;

  stage_pair(A, lda, B, ldb, 0, &lA[0][0][0], &lB[0][0][0]);
  asm volatile("s_waitcnt vmcnt(0)" ::: "memory");
  __syncthreads();
  int cur = 0;
  for (int t = 0; t < nt; ++t) {
    if (t + 1 < nt)
      stage_pair(A, lda, B, ldb, (t + 1) * 64, &lA[cur ^ 1][0][0], &lB[cur ^ 1][0][0]);
    __builtin_amdgcn_s_setprio(1);
#pragma unroll
    for (int ks = 0; ks < 2; ++ks) {
      bf16x8 af[4], bfr[4];
#pragma unroll
      for (int mi = 0; mi < 4; ++mi) {
        const int r = wm + mi * 16 + fr;
        af[mi] = *(const bf16x8*)&lA[cur][r][(ks * 32 + fg) ^ ((r & 7) << 3)];
      }
#pragma unroll
      for (int ni = 0; ni < 4; ++ni) {
        const int r = wn + ni * 16 + fr;
        bfr[ni] = *(const bf16x8*)&lB[cur][r][(ks * 32 + fg) ^ ((r & 7) << 3)];
      }
#pragma unroll
      for (int mi = 0; mi < 4; ++mi)
#pragma unroll
        for (int ni = 0; ni < 4; ++ni)
          acc[mi][ni] = __builtin_amdgcn_mfma_f32_16x16x32_bf16(af[mi], bfr[ni], acc[mi][ni], 0, 0, 0);
    }
    __builtin_amdgcn_s_setprio(0);
    if (t + 1 < nt) {
      asm volatile("s_waitcnt vmcnt(0)" ::: "memory");
      __syncthreads();
      cur ^= 1;
    }
  }
}

// ---------------------------------------------------------------------------
// K3: QKV GEMM. C[o][n] = Wqkv[o][c] x xnT[n][c]^T (+bias).
//   o <  1024 (q,k): transposed store -> qk[b][n][o]
//   o >= 1024 (v)  : natural store    -> v[b][o-1024][n]
// 1D grid 1536 (CPX=192): L -> pair=L/12 (b=pair>>3, n8=pair&7), m=L%12.
// XCD = L/192 = pair/16 = b/2  (12 m-siblings sharing a B-tile + all n of
// 2 batches live on one XCD -> B-tile reads become L2 hits).
// ---------------------------------------------------------------------------
__global__ __launch_bounds__(256, 2) void qkv_gemm_kernel(
    const __bf16* __restrict__ wqb, const __bf16* __restrict__ xnT,
    const float* __restrict__ bqkv, __bf16* __restrict__ qk, __bf16* __restrict__ v) {
  const int L = xcd_swz(192);
  const int pair = L / 12, mblk = L - pair * 12;
  const int b = pair >> 3;
  const int n0 = (pair & 7) * 128, m0 = mblk * 128;
  __shared__ __bf16 lA[2][128][64], lB[2][128][64];
  f32x4 acc[4][4] = {};
  gemm_core_db(wqb + (size_t)m0 * NC, NC, xnT + ((size_t)b * NSPA + n0) * NC, NC,
               NC, lA, lB, acc);

  const int lane = threadIdx.x & 63, wave = threadIdx.x >> 6;
  const int wm = (wave >> 1) * 64, wn = (wave & 1) * 64;
  const int fr = lane & 15, fq4 = (lane >> 4) * 4;
  if (m0 < NSPA) {
#pragma unroll
    for (int mi = 0; mi < 4; ++mi) {
      const int m = m0 + wm + mi * 16 + fq4;
      const float4 bias = *(const float4*)(bqkv + m);
#pragma unroll
      for (int ni = 0; ni < 4; ++ni) {
        const int n = n0 + wn + ni * 16 + fr;
        bf16x4 w;
        w[0] = tob(acc[mi][ni][0] + bias.x);
        w[1] = tob(acc[mi][ni][1] + bias.y);
        w[2] = tob(acc[mi][ni][2] + bias.z);
        w[3] = tob(acc[mi][ni][3] + bias.w);
        *(bf16x4*)(qk + ((size_t)b * NSPA + n) * NSPA + m) = w;
      }
    }
  } else {
#pragma unroll
    for (int mi = 0; mi < 4; ++mi) {
      const int m = m0 + wm + mi * 16 + fq4;        // o index (>=1024)
      const float4 bias = *(const float4*)(bqkv + m);
      const int vr = m - NSPA;
#pragma unroll
      for (int ni = 0; ni < 4; ++ni) {
        const int n = n0 + wn + ni * 16 + fr;
        v[((size_t)b * NC + vr + 0) * NSPA + n] = tob(acc[mi][ni][0] + bias.x);
        v[((size_t)b * NC + vr + 1) * NSPA + n] = tob(acc[mi][ni][1] + bias.y);
        v[((size_t)b * NC + vr + 2) * NSPA + n] = tob(acc[mi][ni][2] + bias.z);
        v[((size_t)b * NC + vr + 3) * NSPA + n] = tob(acc[mi][ni][3] + bias.w);
      }
    }
  }
}

// ---------------------------------------------------------------------------
// K4: scores (swapped). C[j][i] = k[j][d] . q[i][d]; store P[b][i][j] * SCL.
// 1D grid 1024 (CPX=128): L -> b=L>>6, r=L&63, i=r>>3, j=r&7. XCD = b/2.
// ---------------------------------------------------------------------------
__global__ __launch_bounds__(256, 2) void scores_kernel(const __bf16* __restrict__ qk,
                                                        __bf16* __restrict__ P) {
  const int L = xcd_swz(128);
  const int b = L >> 6, r = L & 63;
  const int i0 = (r >> 3) * 128, j0 = (r & 7) * 128;
  const __bf16* base = qk + (size_t)b * NSPA * NSPA;
  __shared__ __bf16 lA[2][128][64], lB[2][128][64];
  f32x4 acc[4][4] = {};
  gemm_core_db(base + (size_t)j0 * NSPA + NC, NSPA, base + (size_t)i0 * NSPA, NSPA,
               NC, lA, lB, acc);

  const int lane = threadIdx.x & 63, wave = threadIdx.x >> 6;
  const int wm = (wave >> 1) * 64, wn = (wave & 1) * 64;
  const int fr = lane & 15, fq4 = (lane >> 4) * 4;
#pragma unroll
  for (int mi = 0; mi < 4; ++mi) {
    const int j = j0 + wm + mi * 16 + fq4;
#pragma unroll
    for (int ni = 0; ni < 4; ++ni) {
      const int i = i0 + wn + ni * 16 + fr;
      bf16x4 w;
      w[0] = tob(acc[mi][ni][0] * SCL);
      w[1] = tob(acc[mi][ni][1] * SCL);
      w[2] = tob(acc[mi][ni][2] * SCL);
      w[3] = tob(acc[mi][ni][3] * SCL);
      *(bf16x4*)(P + ((size_t)b * NSPA + i) * NSPA + j) = w;
    }
  }
}

// ---------------------------------------------------------------------------
// K5: in-place row softmax, wave-per-row, 16 rows/block (4 waves x 4 rows).
// 1D grid 1024 (CPX=128): b = L>>6 -> XCD = b/2.
// ---------------------------------------------------------------------------
__global__ void softmax_kernel(__bf16* __restrict__ P) {
  const int L = xcd_swz(128);
  const int base_row = L * 16 + (threadIdx.x >> 6) * 4;
  const int lane = threadIdx.x & 63;
#pragma unroll
  for (int r = 0; r < 4; ++r) {
    __bf16* p = P + (size_t)(base_row + r) * NSPA + lane * 16;
    bf16x8 v0 = *(const bf16x8*)p;
    bf16x8 v1 = *(const bf16x8*)(p + 8);
    float f[16];
#pragma unroll
    for (int i = 0; i < 8; ++i) { f[i] = (float)v0[i]; f[8 + i] = (float)v1[i]; }
    float m = f[0];
#pragma unroll
    for (int i = 1; i < 16; ++i) m = fmaxf(m, f[i]);
#pragma unroll
    for (int off = 32; off; off >>= 1) m = fmaxf(m, __shfl_xor(m, off));
    float s = 0.f;
#pragma unroll
    for (int i = 0; i < 16; ++i) { f[i] = __expf(f[i] - m); s += f[i]; }
#pragma unroll
    for (int off = 32; off; off >>= 1) s += __shfl_xor(s, off);
    const float inv = 1.f / s;
#pragma unroll
    for (int i = 0; i < 8; ++i) { v0[i] = tob(f[i] * inv); v1[i] = tob(f[8 + i] * inv); }
    *(bf16x8*)p = v0;
    *(bf16x8*)(p + 8) = v1;
  }
}

// ---------------------------------------------------------------------------
// K6: PV. C[d][i] = v[d][j] . P[i][j]; transposed store -> attn[b][i][d].
// 1D grid 512 (CPX=64): L -> b=L>>5, r=L&31, d=r>>3, i=r&7. XCD = b/2.
// ---------------------------------------------------------------------------
__global__ __launch_bounds__(256, 2) void pv_kernel(const __bf16* __restrict__ v,
                                                    const __bf16* __restrict__ P,
                                                    __bf16* __restrict__ attn) {
  const int L = xcd_swz(64);
  const int b = L >> 5, r = L & 31;
  const int d0 = (r >> 3) * 128, i0 = (r & 7) * 128;
  __shared__ __bf16 lA[2][128][64], lB[2][128][64];
  f32x4 acc[4][4] = {};
  gemm_core_db(v + ((size_t)b * NC + d0) * NSPA, NSPA,
               P + ((size_t)b * NSPA + i0) * NSPA, NSPA, NSPA, lA, lB, acc);

  const int lane = threadIdx.x & 63, wave = threadIdx.x >> 6;
  const int wm = (wave >> 1) * 64, wn = (wave & 1) * 64;
  const int fr = lane & 15, fq4 = (lane >> 4) * 4;
#pragma unroll
  for (int mi = 0; mi < 4; ++mi) {
    const int d = d0 + wm + mi * 16 + fq4;
#pragma unroll
    for (int ni = 0; ni < 4; ++ni) {
      const int i = i0 + wn + ni * 16 + fr;
      bf16x4 w;
      w[0] = tob(acc[mi][ni][0]);
      w[1] = tob(acc[mi][ni][1]);
      w[2] = tob(acc[mi][ni][2]);
      w[3] = tob(acc[mi][ni][3]);
      *(bf16x4*)(attn + ((size_t)b * NSPA + i) * NC + d) = w;
    }
  }
}

// ---------------------------------------------------------------------------
// K7: out-proj. C[o][n] = Wout[o][c] . attn[n][c] + bias + x, fp32 natural.
// 1D grid 512 (CPX=64): L -> b=L>>5, r=L&31, m=r>>3, n=r&7. XCD = b/2.
// ---------------------------------------------------------------------------
__global__ __launch_bounds__(256, 2) void out_gemm_kernel(
    const __bf16* __restrict__ wob, const __bf16* __restrict__ attn,
    const float* __restrict__ bout, const float* __restrict__ x,
    float* __restrict__ out) {
  const int L = xcd_swz(64);
  const int b = L >> 5, r = L & 31;
  const int m0 = (r >> 3) * 128, n0 = (r & 7) * 128;
  __shared__ __bf16 lA[2][128][64], lB[2][128][64];
  f32x4 acc[4][4] = {};
  gemm_core_db(wob + (size_t)m0 * NC, NC, attn + ((size_t)b * NSPA + n0) * NC, NC,
               NC, lA, lB, acc);

  const int lane = threadIdx.x & 63, wave = threadIdx.x >> 6;
  const int wm = (wave >> 1) * 64, wn = (wave & 1) * 64;
  const int fr = lane & 15, fq4 = (lane >> 4) * 4;
#pragma unroll
  for (int mi = 0; mi < 4; ++mi) {
    const int m = m0 + wm + mi * 16 + fq4;
    const float4 bias = *(const float4*)(bout + m);
#pragma unroll
    for (int ni = 0; ni < 4; ++ni) {
      const int n = n0 + wn + ni * 16 + fr;
      const size_t i0x = ((size_t)b * NC + m) * NSPA + n;
      out[i0x + 0 * NSPA] = acc[mi][ni][0] + bias.x + x[i0x + 0 * NSPA];
      out[i0x + 1 * NSPA] = acc[mi][ni][1] + bias.y + x[i0x + 1 * NSPA];
      out[i0x + 2 * NSPA] = acc[mi][ni][2] + bias.z + x[i0x + 2 * NSPA];
      out[i0x + 3 * NSPA] = acc[mi][ni][3] + bias.w + x[i0x + 3 * NSPA];
    }
  }
}

// ---------------------------------------------------------------------------
// Workspace (~66 MB):
//   coefA/coefB: 2x32 KB | xnT/attn: 16 MB | wqb 1.5 MB | wob 0.5 MB
//   v: 16 MB | P: 32 MB.  qk (32 MB) lives in d_out (dead until out_gemm).
// ---------------------------------------------------------------------------
extern "C" void kernel_launch(void* const* d_in, const int* in_sizes, int n_in,
                              void* d_out, int out_size, void* d_ws, size_t ws_size,
                              hipStream_t stream) {
  const float* x        = (const float*)d_in[0];
  const float* gn_scale = (const float*)d_in[3];
  const float* gn_bias  = (const float*)d_in[4];
  const float* w_qkv    = (const float*)d_in[5];
  const float* b_qkv    = (const float*)d_in[6];
  const float* w_out    = (const float*)d_in[7];
  const float* b_out    = (const float*)d_in[8];
  float* out = (float*)d_out;

  char* ws = (char*)d_ws;
  float*  coefA = (float*)ws;                                   // 32 KB
  float*  coefB = coefA + NB * NC;                              // 32 KB
  __bf16* xnT   = (__bf16*)(ws + (64 << 10));                   // 16 MB (also attn)
  __bf16* attn  = xnT;
  __bf16* wqb   = xnT + (size_t)NB * NSPA * NC;                 // 1.5 MB
  __bf16* wob   = wqb + (size_t)NO3 * NC;                       // 0.5 MB
  __bf16* vbuf  = wob + (size_t)NC * NC;                        // 16 MB
  __bf16* P     = vbuf + (size_t)NB * NC * NSPA;                // 32 MB
  __bf16* qk    = (__bf16*)d_out;                               // 32 MB scratch in out

  gn_stats_kernel<<<dim3(512), 256, 0, stream>>>(x, gn_scale, gn_bias, coefA, coefB);
  pack_w_kernel<<<dim3((NO3 * NC + NC * NC) / 4 / 256), 256, 0, stream>>>(w_qkv, w_out, wqb, wob);
  pack_x_kernel<<<dim3(2048), 256, 0, stream>>>(x, coefA, coefB, xnT);
  qkv_gemm_kernel<<<dim3(1536), 256, 0, stream>>>(wqb, xnT, b_qkv, qk, vbuf);
  scores_kernel<<<dim3(1024), 256, 0, stream>>>(qk, P);
  softmax_kernel<<<dim3(1024), 256, 0, stream>>>(P);
  pv_kernel<<<dim3(512), 256, 0, stream>>>(vbuf, P, attn);
  out_gemm_kernel<<<dim3(512), 256, 0, stream>>>(wob, attn, b_out, x, out);
}